// Round 1
// baseline (112.159 us; speedup 1.0000x reference)
//
#include <hip/hip_runtime.h>

// VQC simulation: one 64-lane wave per batch element.
// State: 256 complex amps = 4 complex per lane in registers.
// idx = lane*4 + r ; qubit q <-> idx bit (7-q):
//   q=0..5 <-> lane bit (5-q)   (cross-lane via shfl_xor)
//   q=6    <-> r bit 1          (register ops)
//   q=7    <-> r bit 0          (register ops)

__global__ __launch_bounds__(256) void vqc_kernel(
    const float* __restrict__ inputs,   // (B, 8)
    const float* __restrict__ weights,  // (2, 8)
    float* __restrict__ out)            // (B, 8)
{
    const int lane = threadIdx.x & 63;
    const int b = (blockIdx.x << 2) + (threadIdx.x >> 6);  // 4 waves / block

    // ---- encoding angles (per-element) ----
    float ci[8], si[8];
#pragma unroll
    for (int q = 0; q < 8; ++q) {
        const float x = 0.5f * inputs[b * 8 + q];
        ci[q] = __cosf(x);
        si[q] = __sinf(x);
    }

    // ---- initial product state |psi> = RY(x) |0...0> (all-real amplitudes) ----
    float common = 1.0f;
#pragma unroll
    for (int q = 0; q < 6; ++q)
        common *= ((lane >> (5 - q)) & 1) ? si[q] : ci[q];

    float re[4], im[4];
    re[0] = common * ci[6] * ci[7];
    re[1] = common * ci[6] * si[7];
    re[2] = common * si[6] * ci[7];
    re[3] = common * si[6] * si[7];
#pragma unroll
    for (int r = 0; r < 4; ++r) im[r] = 0.0f;

#pragma unroll
    for (int layer = 0; layer < 2; ++layer) {
        // ======== CNOT chain c -> c+1, c = 0..6 ========
        // c=0..4: control = lane bit (5-c), target = lane bit (4-c)
#pragma unroll
        for (int c = 0; c < 5; ++c) {
            const int xm = 1 << (4 - c);
            const int ctrl = (lane >> (5 - c)) & 1;
#pragma unroll
            for (int r = 0; r < 4; ++r) {
                const float pre = __shfl_xor(re[r], xm, 64);
                const float pim = __shfl_xor(im[r], xm, 64);
                re[r] = ctrl ? pre : re[r];
                im[r] = ctrl ? pim : im[r];
            }
        }
        // c=5: control = lane bit 0, target = r bit 1 (cond swap r0<->r2, r1<->r3)
        {
            const int ctrl = lane & 1;
            const float a0 = re[0], a1 = re[1], a2 = re[2], a3 = re[3];
            re[0] = ctrl ? a2 : a0;  re[2] = ctrl ? a0 : a2;
            re[1] = ctrl ? a3 : a1;  re[3] = ctrl ? a1 : a3;
            const float b0 = im[0], b1 = im[1], b2 = im[2], b3 = im[3];
            im[0] = ctrl ? b2 : b0;  im[2] = ctrl ? b0 : b2;
            im[1] = ctrl ? b3 : b1;  im[3] = ctrl ? b1 : b3;
        }
        // c=6: control = r bit 1, target = r bit 0 -> unconditional swap r2<->r3
        {
            float t = re[2]; re[2] = re[3]; re[3] = t;
            t = im[2]; im[2] = im[3]; im[3] = t;
        }

        // ======== RX(theta) on every qubit; RX = [[c,-is],[-is,c]] ========
        // new = c*a - i*s*partner  (same formula both sides of the pair)
        // q = 0..5: cross-lane, xor mask 1<<(5-q)
#pragma unroll
        for (int q = 0; q < 6; ++q) {
            const float x = 0.5f * weights[layer * 8 + q];
            const float cg = __cosf(x);
            const float sg = __sinf(x);
            const int xm = 1 << (5 - q);
#pragma unroll
            for (int r = 0; r < 4; ++r) {
                const float pre = __shfl_xor(re[r], xm, 64);
                const float pim = __shfl_xor(im[r], xm, 64);
                const float nre = cg * re[r] + sg * pim;
                const float nim = cg * im[r] - sg * pre;
                re[r] = nre; im[r] = nim;
            }
        }
        // q = 6: partner is r^2 (in-lane)
        {
            const float x = 0.5f * weights[layer * 8 + 6];
            const float cg = __cosf(x), sg = __sinf(x);
            float nre[4], nim[4];
#pragma unroll
            for (int r = 0; r < 4; ++r) {
                nre[r] = cg * re[r] + sg * im[r ^ 2];
                nim[r] = cg * im[r] - sg * re[r ^ 2];
            }
#pragma unroll
            for (int r = 0; r < 4; ++r) { re[r] = nre[r]; im[r] = nim[r]; }
        }
        // q = 7: partner is r^1 (in-lane)
        {
            const float x = 0.5f * weights[layer * 8 + 7];
            const float cg = __cosf(x), sg = __sinf(x);
            float nre[4], nim[4];
#pragma unroll
            for (int r = 0; r < 4; ++r) {
                nre[r] = cg * re[r] + sg * im[r ^ 1];
                nim[r] = cg * im[r] - sg * re[r ^ 1];
            }
#pragma unroll
            for (int r = 0; r < 4; ++r) { re[r] = nre[r]; im[r] = nim[r]; }
        }
    }

    // ======== measurement: <Z_q> = sum_idx (+/-) |amp|^2 ========
    float p[4];
#pragma unroll
    for (int r = 0; r < 4; ++r) p[r] = re[r] * re[r] + im[r] * im[r];

    const float psum = (p[0] + p[1]) + (p[2] + p[3]);
    float z6 = (p[0] + p[1]) - (p[2] + p[3]);   // qubit 6 <-> r bit 1
    float z7 = (p[0] + p[2]) - (p[1] + p[3]);   // qubit 7 <-> r bit 0

    // Walsh-Hadamard over 64 lanes: lane m ends with sum_L (-1)^{m.L} psum(L).
    // Lane 2^(5-q) then holds <Z_q> for q=0..5 — all six signed sums in one pass.
    float a = psum;
#pragma unroll
    for (int k = 0; k < 6; ++k) {
        const float bv = __shfl_xor(a, 1 << k, 64);
        a = ((lane >> k) & 1) ? (bv - a) : (a + bv);
    }
    // plain butterfly sums for z6, z7 (result in all lanes)
#pragma unroll
    for (int k = 0; k < 6; ++k) z6 += __shfl_xor(z6, 1 << k, 64);
#pragma unroll
    for (int k = 0; k < 6; ++k) z7 += __shfl_xor(z7, 1 << k, 64);

    // gather: lane q (q=0..5) reads WHT value from lane 32>>q; lanes 6,7 use z6,z7
    const int src = (lane < 6) ? (32 >> lane) : 0;
    float v = __shfl(a, src, 64);
    if (lane == 6) v = z6;
    if (lane == 7) v = z7;
    if (lane < 8) out[b * 8 + lane] = v;
}

extern "C" void kernel_launch(void* const* d_in, const int* in_sizes, int n_in,
                              void* d_out, int out_size, void* d_ws, size_t ws_size,
                              hipStream_t stream) {
    const float* inputs  = (const float*)d_in[0];
    const float* weights = (const float*)d_in[1];
    float* out = (float*)d_out;
    const int B = in_sizes[0] / 8;          // 32768
    const int blocks = B / 4;               // 4 waves (= 4 elements) per 256-thread block
    hipLaunchKernelGGL(vqc_kernel, dim3(blocks), dim3(256), 0, stream,
                       inputs, weights, out);
}

// Round 2
// 70.909 us; speedup vs baseline: 1.5817x; 1.5817x over previous
//
#include <hip/hip_runtime.h>

// 8-qubit VQC, CNOT chains folded into RX pairing masks (state stays in the
// original basis; after k chain applications RX_q pairs mask L^-k e_q where
// L = prefix-xor; L^-1 e_q = e_q^e_{q+1}, L^-2 e_q = e_q^e_{q+2}).
// Layout: 2 batch elements per wave64 (one per 32-lane half).
// amp idx = l5*8 + r (l5 = lane&31): qubits 0..4 <-> lane bits 4..0,
// qubit 5 <-> r bit 2, qubit 6 <-> r bit 1, qubit 7 <-> r bit 0.
// All cross-lane masks < 32 -> single ds_swizzle (immediate), serving both
// halves at once. Measurement: <Z_q> needs sign parity bit_q(L^2 x) =
// XOR of x_i (i<=q, i==q mod 2) -> WHT output lanes {16,8,20,10,21} + reg signs.

template<int M>
__device__ __forceinline__ float swz(float x) {
    return __int_as_float(__builtin_amdgcn_ds_swizzle(__float_as_int(x), (M << 10) | 0x1F));
}

// RX-type mixing along mask (LM lane-bits, RX reg-bits): new = c*a - i*s*partner
template<int LM, int RX>
__device__ __forceinline__ void gate_cross(float re[8], float im[8], float cg, float sg) {
    float pr[8], pi[8];
#pragma unroll
    for (int r = 0; r < 8; ++r) {
        pr[r] = swz<LM>(re[r ^ RX]);
        pi[r] = swz<LM>(im[r ^ RX]);
    }
#pragma unroll
    for (int r = 0; r < 8; ++r) {
        const float nr = cg * re[r] + sg * pi[r];
        const float ni = cg * im[r] - sg * pr[r];
        re[r] = nr; im[r] = ni;
    }
}

template<int RX>
__device__ __forceinline__ void gate_local(float re[8], float im[8], float cg, float sg) {
    float pr[8], pi[8];
#pragma unroll
    for (int r = 0; r < 8; ++r) { pr[r] = re[r ^ RX]; pi[r] = im[r ^ RX]; }
#pragma unroll
    for (int r = 0; r < 8; ++r) {
        const float nr = cg * re[r] + sg * pi[r];
        const float ni = cg * im[r] - sg * pr[r];
        re[r] = nr; im[r] = ni;
    }
}

__global__ void trig_kernel(const float* __restrict__ w, float* __restrict__ trig) {
    const int j = threadIdx.x;
    if (j < 16) {
        const float x = 0.5f * w[j];
        trig[j]      = __cosf(x);
        trig[16 + j] = __sinf(x);
    }
}

__global__ __launch_bounds__(256) void vqc_kernel(
    const float* __restrict__ inputs,   // (B, 8)
    const float* __restrict__ weights,  // (2, 8) — fallback only
    const float* __restrict__ trig,     // 32 floats: [j]=cos(w_j/2), [16+j]=sin
    float* __restrict__ out)            // (B, 8)
{
    const int l5 = threadIdx.x & 31;
    const int b  = blockIdx.x * 8 + (threadIdx.x >> 5);   // one element per half-wave

    // ---- weight trig (wave-uniform -> SGPRs) ----
    float tc[16], tsn[16];
    if (trig != nullptr) {
#pragma unroll
        for (int j = 0; j < 16; ++j) { tc[j] = trig[j]; tsn[j] = trig[16 + j]; }
    } else {
#pragma unroll
        for (int j = 0; j < 16; ++j) {
            const float x = 0.5f * weights[j];
            tc[j] = __cosf(x); tsn[j] = __sinf(x);
        }
    }

    // ---- encoding angles ----
    const float4* in4 = (const float4*)inputs + (size_t)b * 2;
    const float4 i0 = in4[0], i1 = in4[1];
    const float c0 = __cosf(0.5f * i0.x), s0 = __sinf(0.5f * i0.x);
    const float c1 = __cosf(0.5f * i0.y), s1 = __sinf(0.5f * i0.y);
    const float c2 = __cosf(0.5f * i0.z), s2 = __sinf(0.5f * i0.z);
    const float c3 = __cosf(0.5f * i0.w), s3 = __sinf(0.5f * i0.w);
    const float c4 = __cosf(0.5f * i1.x), s4 = __sinf(0.5f * i1.x);
    const float c5 = __cosf(0.5f * i1.y), s5 = __sinf(0.5f * i1.y);
    const float c6 = __cosf(0.5f * i1.z), s6 = __sinf(0.5f * i1.z);
    const float c7 = __cosf(0.5f * i1.w), s7 = __sinf(0.5f * i1.w);

    // ---- initial product state RY(x)|0..0> (all real) ----
    float common = ((l5 >> 4) & 1 ? s0 : c0);
    common      *= ((l5 >> 3) & 1 ? s1 : c1);
    common      *= ((l5 >> 2) & 1 ? s2 : c2);
    common      *= ((l5 >> 1) & 1 ? s3 : c3);
    common      *= ( l5       & 1 ? s4 : c4);

    const float cc = c6 * c7, cs = c6 * s7, sc = s6 * c7, ss = s6 * s7;
    const float m5c = common * c5, m5s = common * s5;
    float re[8], im[8];
    re[0] = m5c * cc; re[1] = m5c * cs; re[2] = m5c * sc; re[3] = m5c * ss;
    re[4] = m5s * cc; re[5] = m5s * cs; re[6] = m5s * sc; re[7] = m5s * ss;
#pragma unroll
    for (int r = 0; r < 8; ++r) im[r] = 0.0f;

    // ---- layer 1: masks e_q ^ e_{q+1} ----
    gate_cross<24, 0>(re, im, tc[0], tsn[0]);   // q0: qubits {0,1} -> lanes {4,3}
    gate_cross<12, 0>(re, im, tc[1], tsn[1]);   // q1
    gate_cross< 6, 0>(re, im, tc[2], tsn[2]);   // q2
    gate_cross< 3, 0>(re, im, tc[3], tsn[3]);   // q3
    gate_cross< 1, 4>(re, im, tc[4], tsn[4]);   // q4: lane0 + reg bit2
    gate_local< 6   >(re, im, tc[5], tsn[5]);   // q5: reg bits {2,1}
    gate_local< 3   >(re, im, tc[6], tsn[6]);   // q6: reg bits {1,0}
    gate_local< 1   >(re, im, tc[7], tsn[7]);   // q7: reg bit 0

    // ---- layer 2: masks e_q ^ e_{q+2} ----
    gate_cross<20, 0>(re, im, tc[ 8], tsn[ 8]); // q0: lanes {4,2}
    gate_cross<10, 0>(re, im, tc[ 9], tsn[ 9]); // q1
    gate_cross< 5, 0>(re, im, tc[10], tsn[10]); // q2
    gate_cross< 2, 4>(re, im, tc[11], tsn[11]); // q3: lane1 + reg bit2
    gate_cross< 1, 2>(re, im, tc[12], tsn[12]); // q4: lane0 + reg bit1
    gate_local< 5   >(re, im, tc[13], tsn[13]); // q5: reg bits {2,0}
    gate_local< 2   >(re, im, tc[14], tsn[14]); // q6: reg bit 1
    gate_local< 1   >(re, im, tc[15], tsn[15]); // q7: reg bit 0

    // ---- measurement ----
    float p[8];
#pragma unroll
    for (int r = 0; r < 8; ++r) p[r] = re[r] * re[r] + im[r] * im[r];

    float A  = ((p[0] + p[1]) + (p[2] + p[3])) + ((p[4] + p[5]) + (p[6] + p[7])); // psum
    float Bv = ((p[0] + p[1]) + (p[2] + p[3])) - ((p[4] + p[5]) + (p[6] + p[7])); // sign r bit2
    float Cv = ((p[0] + p[1]) + (p[4] + p[5])) - ((p[2] + p[3]) + (p[6] + p[7])); // sign r bit1
    float Dv = ((p[0] + p[2]) + (p[5] + p[7])) - ((p[1] + p[3]) + (p[4] + p[6])); // sign r bit2^bit0

    // 5-stage WHT over each 32-lane half: lane m ends with sum_l (-1)^{m.l} v[l]
#define WHT_STAGE(K)                                                        \
    {                                                                       \
        const float bA = swz<(1 << K)>(A);                                  \
        const float bB = swz<(1 << K)>(Bv);                                 \
        const float bC = swz<(1 << K)>(Cv);                                 \
        const float bD = swz<(1 << K)>(Dv);                                 \
        const bool ng = (l5 >> K) & 1;                                      \
        A  = ng ? (bA - A)  : (A + bA);                                     \
        Bv = ng ? (bB - Bv) : (Bv + bB);                                    \
        Cv = ng ? (bC - Cv) : (Cv + bC);                                    \
        Dv = ng ? (bD - Dv) : (Dv + bD);                                    \
    }
    WHT_STAGE(0) WHT_STAGE(1) WHT_STAGE(2) WHT_STAGE(3) WHT_STAGE(4)
#undef WHT_STAGE

    // out lanes (per half): q0=A@16, q1=A@8, q2=A@20, q3=A@10, q4=A@21,
    //                       q5=B@10, q6=C@21, q7=D@10
    float* o = out + (size_t)b * 8;
    if      (l5 == 16) { o[0] = A; }
    else if (l5 ==  8) { o[1] = A; }
    else if (l5 == 20) { o[2] = A; }
    else if (l5 == 10) { o[3] = A; o[5] = Bv; o[7] = Dv; }
    else if (l5 == 21) { o[4] = A; o[6] = Cv; }
}

extern "C" void kernel_launch(void* const* d_in, const int* in_sizes, int n_in,
                              void* d_out, int out_size, void* d_ws, size_t ws_size,
                              hipStream_t stream) {
    const float* inputs  = (const float*)d_in[0];
    const float* weights = (const float*)d_in[1];
    float* out = (float*)d_out;
    const int B = in_sizes[0] / 8;          // 32768

    float* trig = nullptr;
    if (ws_size >= 32 * sizeof(float)) {
        trig = (float*)d_ws;
        hipLaunchKernelGGL(trig_kernel, dim3(1), dim3(64), 0, stream, weights, trig);
    }
    hipLaunchKernelGGL(vqc_kernel, dim3(B / 8), dim3(256), 0, stream,
                       inputs, weights, trig, out);
}